// Round 14
// baseline (139.929 us; speedup 1.0000x reference)
//
#include <hip/hip_runtime.h>
#include <hip/hip_bf16.h>

typedef float f4 __attribute__((ext_vector_type(4)));
typedef int   i4 __attribute__((ext_vector_type(4)));
typedef unsigned short us8 __attribute__((ext_vector_type(8)));
typedef short bfrag __attribute__((ext_vector_type(8)));     // 8 bf16
typedef float f16v __attribute__((ext_vector_type(16)));

constexpr int NN   = 4096;
constexpr int FINc = 512;
constexpr int FOUTc= 128;
constexpr int KHc  = 4;
constexpr int KFc  = 512;
constexpr float LOG2E = 1.44269504088896340736f;

static __device__ __forceinline__ unsigned short f2bf(float f) {
    unsigned u = __float_as_uint(f);
    return (unsigned short)((u + 0x7fffu + ((u >> 16) & 1u)) >> 16);   // RNE
}
static __device__ __forceinline__ float bf2f(unsigned short u) {
    return __uint_as_float(((unsigned)u) << 16);
}
static __device__ __forceinline__ bfrag us2bf(us8 v) {
    union { us8 u; bfrag s; } cv; cv.u = v; return cv.s;
}

// hB fragment layout (bf16): per head k, per 64-m chunk mc:
//   byte = k*1048576 + mc*16384 + ks*4096 + lg*2048 + col*16 + j*2
// where m = ks*16 + lg*8 + j, col in [0,128)

// ---------------- kernel 0: prep: x->xb (bf16) | W -> WbT[k][o][f] ----------------
__global__ __launch_bounds__(256) void prep_kernel(const float* __restrict__ x,
                                                   const float* __restrict__ W,
                                                   unsigned short* __restrict__ xb,
                                                   unsigned short* __restrict__ WbT) {
    __shared__ float tile[32 * 132];
    const int b = blockIdx.x, t = threadIdx.x;
    if (b < 1024) {                       // x cast: 8 per thread
        size_t base = ((size_t)b * 256 + t) * 8;
        f4 v0 = *(const f4*)&x[base];
        f4 v1 = *(const f4*)&x[base + 4];
        us8 o;
#pragma unroll
        for (int j = 0; j < 4; ++j) { o[j] = f2bf(v0[j]); o[4 + j] = f2bf(v1[j]); }
        *(us8*)&xb[base] = o;
    } else {                              // W transpose: 64 blocks, 32f x 128o tiles
        const int wb = b - 1024;
        const int k = wb >> 4, f0 = (wb & 15) * 32;
#pragma unroll
        for (int p = 0; p < 4; ++p) {
            int fl = p * 8 + (t >> 5);
            int oc = (t & 31) * 4;
            *(f4*)&tile[fl * 132 + oc] =
                *(const f4*)&W[(size_t)k * 65536 + (size_t)(f0 + fl) * 128 + oc];
        }
        __syncthreads();
        const int o = t >> 1, fh = (t & 1) * 16;
        alignas(16) unsigned short buf[16];
#pragma unroll
        for (int j = 0; j < 16; ++j) buf[j] = f2bf(tile[(fh + j) * 132 + o]);
        unsigned short* dst = &WbT[((size_t)k * 128 + o) * FINc + f0 + fh];
        *(us8*)dst       = *(const us8*)&buf[0];
        *(us8*)(dst + 8) = *(const us8*)&buf[8];
    }
}

// ---------------- kernel 1: gemmh (blocks 0..511) | adj->bits (blocks 512..1535) ----------------
__global__ __launch_bounds__(256) void gemmh_bits_kernel(const unsigned short* __restrict__ xb,
                                                         const unsigned short* __restrict__ WbT,
                                                         const int* __restrict__ adj,
                                                         unsigned short* __restrict__ hB,
                                                         unsigned* __restrict__ bits) {
    __shared__ char Ax[64 * 128];
    __shared__ char Bx[64 * 128];
    const int b = blockIdx.x, t = threadIdx.x;
    if (b >= 512) {                       // ---- bits: 1024 blocks x 16384 ints ----
        size_t i0 = (size_t)(b - 512) * 16384 + (size_t)t * 64;
        const int* ap = adj + i0;
        unsigned long long bb = 0ull;
#pragma unroll
        for (int c = 0; c < 16; ++c) {
            i4 v = *(const i4*)(ap + c * 4);
            unsigned n = (v[0] != 0 ? 1u : 0u) | (v[1] != 0 ? 2u : 0u)
                       | (v[2] != 0 ? 4u : 0u) | (v[3] != 0 ? 8u : 0u);
            bb |= (unsigned long long)n << (c * 4);
        }
        *(unsigned long long*)&bits[i0 >> 5] = bb;
        return;
    }
    const int wid = t >> 6, lane = t & 63;
    const int c0 = (b & 7) * 64, n0 = (b >> 3) * 64;
    const int head = c0 >> 7, ob = c0 & 127;
    const int srow = t >> 2, sseg = t & 3;
    const unsigned short* asrc = &xb[(size_t)(n0 + srow) * FINc + sseg * 16];
    const unsigned short* bsrc = &WbT[((size_t)(head * 128 + ob + srow)) * FINc + sseg * 16];
    const int rowbase = (wid & 1) * 32, colbase = (wid >> 1) * 32;
    f16v acc = {};
    for (int fc = 0; fc < FINc; fc += 64) {
        us8 a0 = *(const us8*)(asrc + fc), a1 = *(const us8*)(asrc + fc + 8);
        us8 b0 = *(const us8*)(bsrc + fc), b1 = *(const us8*)(bsrc + fc + 8);
        __syncthreads();
        {
            int byt = (sseg * 32) ^ ((srow & 7) << 4);
            char* pa = Ax + srow * 128;
            *(us8*)(pa + byt) = a0;  *(us8*)(pa + (byt ^ 16)) = a1;
            char* pb = Bx + srow * 128;
            *(us8*)(pb + byt) = b0;  *(us8*)(pb + (byt ^ 16)) = b1;
        }
        __syncthreads();
#pragma unroll
        for (int ks = 0; ks < 4; ++ks) {
            int kb = ks * 32 + ((lane >> 5) << 4);
            int ar = rowbase + (lane & 31);
            bfrag af = *(const bfrag*)(Ax + ar * 128 + (kb ^ ((ar & 7) << 4)));
            int bc = colbase + (lane & 31);
            bfrag bf = *(const bfrag*)(Bx + bc * 128 + (kb ^ ((bc & 7) << 4)));
            acc = __builtin_amdgcn_mfma_f32_32x32x16_bf16(af, bf, acc, 0, 0, 0);
        }
    }
    __syncthreads();
#pragma unroll
    for (int reg = 0; reg < 16; ++reg) {
        int row = rowbase + (reg & 3) + 8 * (reg >> 2) + 4 * (lane >> 5);
        int col = colbase + (lane & 31);
        *(unsigned short*)(Ax + row * 128 + ((col * 2) ^ ((row & 7) << 4))) = f2bf(acc[reg]);
    }
    __syncthreads();
    {
        const int col_l = t & 63;
        unsigned short* dstbase = hB + (size_t)head * 524288 + (size_t)(n0 >> 6) * 8192
                                     + (size_t)(ob + col_l) * 8;
#pragma unroll
        for (int g = 0; g < 2; ++g) {
            int o8 = (t >> 6) + g * 4;
            int ks = o8 >> 1, lg = o8 & 1;
            alignas(16) unsigned short buf[8];
#pragma unroll
            for (int j = 0; j < 8; ++j) {
                int r = o8 * 8 + j;
                buf[j] = *(const unsigned short*)(Ax + r * 128 + ((col_l * 2) ^ ((r & 7) << 4)));
            }
            *(us8*)(dstbase + ks * 2048 + lg * 1024) = *(const us8*)buf;
        }
    }
}

// ---------------- kernel 2: ei[n,k], ejT[k,n] from hB (pre-scaled by log2e) ----------------
__global__ __launch_bounds__(256) void e2_kernel(const unsigned short* __restrict__ hB,
                                                 const float* __restrict__ a,
                                                 float* __restrict__ ei,
                                                 float* __restrict__ ejT) {
    __shared__ unsigned short hs[8192];
    __shared__ float as[128], ad[128];
    __shared__ float pim[4][64], pjm[4][64];
    const int t = threadIdx.x;
    const int k = blockIdx.x >> 6;
    const int mc = blockIdx.x & 63;
    if (t < 128) as[t] = a[k * 256 + t] * LOG2E;
    else         ad[t - 128] = a[k * 256 + t] * LOG2E;
    const unsigned short* src = hB + ((size_t)k * 64 + mc) * 8192;
#pragma unroll
    for (int i = 0; i < 4; ++i) {
        int off = i * 2048 + t * 8;
        *(us8*)&hs[off] = *(const us8*)&src[off];
    }
    __syncthreads();
    const int m = t & 63, wq = t >> 6;
    const int base = (m >> 4) * 2048 + ((m >> 3) & 1) * 1024 + (m & 7);
    float si = 0.f, sj = 0.f;
#pragma unroll
    for (int cc = 0; cc < 32; ++cc) {
        int c = wq * 32 + cc;
        float v = bf2f(hs[base + c * 8]);
        si += v * as[c];
        sj += v * ad[c];
    }
    pim[wq][m] = si; pjm[wq][m] = sj;
    __syncthreads();
    if (t < 64) {
        ei[(mc * 64 + t) * KHc + k]        = pim[0][t] + pim[1][t] + pim[2][t] + pim[3][t];
        ejT[(size_t)k * NN + mc * 64 + t]  = pjm[0][t] + pjm[1][t] + pjm[2][t] + pjm[3][t];
    }
}

// ---------------- kernel 3: out = softmax(P) @ H, full m, 8 waves ----------------
// 512 blocks x 512 threads; 8 waves x private 512-m slice, register-P, zero
// in-loop barriers. Flat 32-step loop, 1-step software-pipelined B-fragment
// prefetch (hides L2 latency), setprio around MFMA cluster. Factorized P-gen.
__global__ __launch_bounds__(512, 4) void out_mfma_kernel(const unsigned* __restrict__ bits,
                                                          const float* __restrict__ ei,
                                                          const float* __restrict__ ejT,
                                                          const unsigned short* __restrict__ hB,
                                                          float* __restrict__ out) {
    __shared__ unsigned bitsL[8][544];      // 32 rows x 17 (16 words + pad) per wave
    __shared__ float ejPL[4096];            // [8][512]; reused as red after loop
    __shared__ float ejNL[4096];            // [8][512]
    __shared__ float sred[8][32];
    __shared__ float lsum[32];
    const int bid = blockIdx.x;
    const int nb  = (bid & 7) * 64 + (bid >> 3);    // bijective: 512 = 8*64
    const int k   = nb >> 7;
    const int n0  = (nb & 127) * 32;
    const int t = threadIdx.x, lane = t & 63, w = t >> 6;
    const int row = lane & 31, kh = lane >> 5;
    const int mq  = w * 512;                        // wave's private m range
    {   // stage bits (wave-private): lane pair covers one row (16 words)
        int r = lane >> 1, cb = (lane & 1) * 8;
        const unsigned* src = &bits[(size_t)(n0 + r) * 128 + (mq >> 5) + cb];
        unsigned* dst = &bitsL[w][r * 17 + cb];
#pragma unroll
        for (int c = 0; c < 8; ++c) dst[c] = src[c];
    }
    {   // stage EjP/EjN (wave-private): 8 columns per lane, exp2 once per column
        const float* src = &ejT[(size_t)k * NN + mq + lane * 8];
        f4 v0 = *(const f4*)src;
        f4 v1 = *(const f4*)(src + 4);
        float* dP = &ejPL[w * 512 + lane * 8];
        float* dN = &ejNL[w * 512 + lane * 8];
#pragma unroll
        for (int c = 0; c < 4; ++c) {
            dP[c]     = exp2f(v0[c]);
            dP[c + 4] = exp2f(v1[c]);
            dN[c]     = exp2f(0.2f * v0[c]);
            dN[c + 4] = exp2f(0.2f * v1[c]);
        }
    }
    const float eiv = ei[(n0 + row) * KHc + k];
    const float C = exp2f(-0.8f * eiv);
    const char* hp = (const char*)hB + (size_t)k * 1048576 + (size_t)(mq >> 6) * 16384
                     + kh * 2048 + row * 16;
    bfrag ones;
#pragma unroll
    for (int j = 0; j < 8; ++j) ones[j] = (short)0x3F80;   // bf16 1.0
    f16v acc0 = {}, acc1 = {}, acc2 = {}, acc3 = {}, accs = {};

    // software pipeline: prefetch step 0
    us8 c0v = *(const us8*)(hp);
    us8 c1v = *(const us8*)(hp + 512);
    us8 c2v = *(const us8*)(hp + 1024);
    us8 c3v = *(const us8*)(hp + 1536);

#pragma unroll 2
    for (int s = 0; s < 32; ++s) {
        const char* hn = hp + 4096;
        // prefetch step s+1 (at s=31 reads <=2KB past plane: still inside d_ws, discarded)
        us8 n0v = *(const us8*)(hn);
        us8 n1v = *(const us8*)(hn + 512);
        us8 n2v = *(const us8*)(hn + 1024);
        us8 n3v = *(const us8*)(hn + 1536);
        // P-gen for step s
        unsigned bw = bitsL[w][row * 17 + (s >> 1)] >> (((s & 1) << 4) + kh * 8);
        const int eb = w * 512 + s * 16 + kh * 8;
        f4 jp0 = *(const f4*)&ejPL[eb];
        f4 jp1 = *(const f4*)&ejPL[eb + 4];
        f4 jn0 = *(const f4*)&ejNL[eb];
        f4 jn1 = *(const f4*)&ejNL[eb + 4];
        float p[8];
#pragma unroll
        for (int j = 0; j < 8; ++j) {
            float jp = (j < 4) ? jp0[j] : jp1[j - 4];
            float jn = (j < 4) ? jn0[j] : jn1[j - 4];
            float v = fmaxf(jp, C * jn);           // exp2(lrelu(s))/exp2(ei)
            p[j] = ((bw >> j) & 1) ? v : 0.f;
        }
        union { unsigned u[4]; bfrag s2; } pk;
#pragma unroll
        for (int j = 0; j < 4; ++j) {
            float2 fp; fp.x = p[2 * j]; fp.y = p[2 * j + 1];
            __hip_bfloat162 b2 = __float22bfloat162_rn(fp);
            pk.u[j] = *reinterpret_cast<unsigned*>(&b2);
        }
        __builtin_amdgcn_s_setprio(1);
        acc0 = __builtin_amdgcn_mfma_f32_32x32x16_bf16(pk.s2, us2bf(c0v), acc0, 0, 0, 0);
        acc1 = __builtin_amdgcn_mfma_f32_32x32x16_bf16(pk.s2, us2bf(c1v), acc1, 0, 0, 0);
        acc2 = __builtin_amdgcn_mfma_f32_32x32x16_bf16(pk.s2, us2bf(c2v), acc2, 0, 0, 0);
        acc3 = __builtin_amdgcn_mfma_f32_32x32x16_bf16(pk.s2, us2bf(c3v), acc3, 0, 0, 0);
        accs = __builtin_amdgcn_mfma_f32_32x32x16_bf16(pk.s2, ones, accs, 0, 0, 0);
        __builtin_amdgcn_s_setprio(0);
        c0v = n0v; c1v = n1v; c2v = n2v; c3v = n3v;
        hp = hn;
    }
    // publish per-wave row sums
    if (row == 0) {   // lanes 0 and 32 of each wave
#pragma unroll
        for (int reg = 0; reg < 16; ++reg) {
            int r = (reg & 3) + 8 * (reg >> 2) + 4 * kh;
            sred[w][r] = accs[reg];
        }
    }
    __syncthreads();
    if (t < 32) {
        float s = ((sred[0][t] + sred[1][t]) + (sred[2][t] + sred[3][t]))
                + ((sred[4][t] + sred[5][t]) + (sred[6][t] + sred[7][t]));
        lsum[t] = 1.0f / s;
    }
    // sequential reduce of acc partials into w0 (red overlays dead ejPL plane)
    float* red = ejPL;
#pragma unroll
    for (int src = 1; src < 8; ++src) {
        if (w == src) {
#pragma unroll
            for (int cg = 0; cg < 4; ++cg) {
                const f16v& av = (cg == 0) ? acc0 : (cg == 1) ? acc1 : (cg == 2) ? acc2 : acc3;
#pragma unroll
                for (int reg = 0; reg < 16; ++reg) {
                    int r = (reg & 3) + 8 * (reg >> 2) + 4 * kh;
                    red[r * 128 + cg * 32 + row] = av[reg];
                }
            }
        }
        __syncthreads();
        if (w == 0) {
#pragma unroll
            for (int cg = 0; cg < 4; ++cg) {
                f16v& av = (cg == 0) ? acc0 : (cg == 1) ? acc1 : (cg == 2) ? acc2 : acc3;
#pragma unroll
                for (int reg = 0; reg < 16; ++reg) {
                    int r = (reg & 3) + 8 * (reg >> 2) + 4 * kh;
                    av[reg] += red[r * 128 + cg * 32 + row];
                }
            }
        }
        __syncthreads();
    }
    if (w == 0) {
#pragma unroll
        for (int cg = 0; cg < 4; ++cg) {
            const f16v& av = (cg == 0) ? acc0 : (cg == 1) ? acc1 : (cg == 2) ? acc2 : acc3;
#pragma unroll
            for (int reg = 0; reg < 16; ++reg) {
                int r = (reg & 3) + 8 * (reg >> 2) + 4 * kh;
                out[(size_t)(n0 + r) * KFc + k * FOUTc + cg * 32 + row] = av[reg] * lsum[r];
            }
        }
    }
}

extern "C" void kernel_launch(void* const* d_in, const int* in_sizes, int n_in,
                              void* d_out, int out_size, void* d_ws, size_t ws_size,
                              hipStream_t stream) {
    const float* x   = (const float*)d_in[0];
    const int*   adj = (const int*)d_in[1];
    const float* W   = (const float*)d_in[2];
    const float* a   = (const float*)d_in[3];
    float* out = (float*)d_out;
    char* ws = (char*)d_ws;

    unsigned short* hB   = (unsigned short*)ws;                  // 0..4 MB
    unsigned short* xb   = (unsigned short*)(ws + (4u << 20));   // 4..8 MB
    unsigned short* WbT  = (unsigned short*)(ws + (20u << 20));  // 20..20.5 MB
    unsigned*       bits = (unsigned*)(ws + (21u << 20));        // 21..23 MB
    float*          ei   = (float*)(ws + (23u << 20));           // 64 KB
    float*          ejT  = ei + (size_t)NN * KHc;                // 64 KB

    prep_kernel<<<1088, 256, 0, stream>>>(x, W, xb, WbT);
    gemmh_bits_kernel<<<1536, 256, 0, stream>>>(xb, WbT, adj, hB, bits);
    e2_kernel<<<256, 256, 0, stream>>>(hB, a, ei, ejT);
    out_mfma_kernel<<<512, 512, 0, stream>>>(bits, ei, ejT, hB, out);
}

// Round 15
// 74.230 us; speedup vs baseline: 1.8851x; 1.8851x over previous
//
#include <hip/hip_runtime.h>
#include <hip/hip_bf16.h>

typedef float f4 __attribute__((ext_vector_type(4)));
typedef int   i4 __attribute__((ext_vector_type(4)));
typedef unsigned short us8 __attribute__((ext_vector_type(8)));
typedef short bfrag __attribute__((ext_vector_type(8)));     // 8 bf16
typedef float f16v __attribute__((ext_vector_type(16)));

constexpr int NN   = 4096;
constexpr int FINc = 512;
constexpr int FOUTc= 128;
constexpr int KHc  = 4;
constexpr int KFc  = 512;
constexpr float LOG2E = 1.44269504088896340736f;

static __device__ __forceinline__ unsigned short f2bf(float f) {
    unsigned u = __float_as_uint(f);
    return (unsigned short)((u + 0x7fffu + ((u >> 16) & 1u)) >> 16);   // RNE
}
static __device__ __forceinline__ float bf2f(unsigned short u) {
    return __uint_as_float(((unsigned)u) << 16);
}
static __device__ __forceinline__ bfrag us2bf(us8 v) {
    union { us8 u; bfrag s; } cv; cv.u = v; return cv.s;
}

// hB fragment layout (bf16): per head k, per 64-m chunk mc:
//   byte = k*1048576 + mc*16384 + ks*4096 + lg*2048 + col*16 + j*2
// where m = ks*16 + lg*8 + j, col in [0,128)

// ---------------- kernel 0: prep: x->xb (bf16) | W -> WbT[k][o][f] ----------------
__global__ __launch_bounds__(256) void prep_kernel(const float* __restrict__ x,
                                                   const float* __restrict__ W,
                                                   unsigned short* __restrict__ xb,
                                                   unsigned short* __restrict__ WbT) {
    __shared__ float tile[32 * 132];
    const int b = blockIdx.x, t = threadIdx.x;
    if (b < 1024) {                       // x cast: 8 per thread
        size_t base = ((size_t)b * 256 + t) * 8;
        f4 v0 = *(const f4*)&x[base];
        f4 v1 = *(const f4*)&x[base + 4];
        us8 o;
#pragma unroll
        for (int j = 0; j < 4; ++j) { o[j] = f2bf(v0[j]); o[4 + j] = f2bf(v1[j]); }
        *(us8*)&xb[base] = o;
    } else {                              // W transpose: 64 blocks, 32f x 128o tiles
        const int wb = b - 1024;
        const int k = wb >> 4, f0 = (wb & 15) * 32;
#pragma unroll
        for (int p = 0; p < 4; ++p) {
            int fl = p * 8 + (t >> 5);
            int oc = (t & 31) * 4;
            *(f4*)&tile[fl * 132 + oc] =
                *(const f4*)&W[(size_t)k * 65536 + (size_t)(f0 + fl) * 128 + oc];
        }
        __syncthreads();
        const int o = t >> 1, fh = (t & 1) * 16;
        alignas(16) unsigned short buf[16];
#pragma unroll
        for (int j = 0; j < 16; ++j) buf[j] = f2bf(tile[(fh + j) * 132 + o]);
        unsigned short* dst = &WbT[((size_t)k * 128 + o) * FINc + f0 + fh];
        *(us8*)dst       = *(const us8*)&buf[0];
        *(us8*)(dst + 8) = *(const us8*)&buf[8];
    }
}

// ---------------- kernel 1: gemmh (blocks 0..511) | adj->bits (blocks 512..1535) ----------------
__global__ __launch_bounds__(256) void gemmh_bits_kernel(const unsigned short* __restrict__ xb,
                                                         const unsigned short* __restrict__ WbT,
                                                         const int* __restrict__ adj,
                                                         unsigned short* __restrict__ hB,
                                                         unsigned* __restrict__ bits) {
    __shared__ char Ax[64 * 128];
    __shared__ char Bx[64 * 128];
    const int b = blockIdx.x, t = threadIdx.x;
    if (b >= 512) {                       // ---- bits: 1024 blocks x 16384 ints ----
        size_t i0 = (size_t)(b - 512) * 16384 + (size_t)t * 64;
        const int* ap = adj + i0;
        unsigned long long bb = 0ull;
#pragma unroll
        for (int c = 0; c < 16; ++c) {
            i4 v = *(const i4*)(ap + c * 4);
            unsigned n = (v[0] != 0 ? 1u : 0u) | (v[1] != 0 ? 2u : 0u)
                       | (v[2] != 0 ? 4u : 0u) | (v[3] != 0 ? 8u : 0u);
            bb |= (unsigned long long)n << (c * 4);
        }
        *(unsigned long long*)&bits[i0 >> 5] = bb;
        return;
    }
    const int wid = t >> 6, lane = t & 63;
    const int c0 = (b & 7) * 64, n0 = (b >> 3) * 64;
    const int head = c0 >> 7, ob = c0 & 127;
    const int srow = t >> 2, sseg = t & 3;
    const unsigned short* asrc = &xb[(size_t)(n0 + srow) * FINc + sseg * 16];
    const unsigned short* bsrc = &WbT[((size_t)(head * 128 + ob + srow)) * FINc + sseg * 16];
    const int rowbase = (wid & 1) * 32, colbase = (wid >> 1) * 32;
    f16v acc = {};
    for (int fc = 0; fc < FINc; fc += 64) {
        us8 a0 = *(const us8*)(asrc + fc), a1 = *(const us8*)(asrc + fc + 8);
        us8 b0 = *(const us8*)(bsrc + fc), b1 = *(const us8*)(bsrc + fc + 8);
        __syncthreads();
        {
            int byt = (sseg * 32) ^ ((srow & 7) << 4);
            char* pa = Ax + srow * 128;
            *(us8*)(pa + byt) = a0;  *(us8*)(pa + (byt ^ 16)) = a1;
            char* pb = Bx + srow * 128;
            *(us8*)(pb + byt) = b0;  *(us8*)(pb + (byt ^ 16)) = b1;
        }
        __syncthreads();
#pragma unroll
        for (int ks = 0; ks < 4; ++ks) {
            int kb = ks * 32 + ((lane >> 5) << 4);
            int ar = rowbase + (lane & 31);
            bfrag af = *(const bfrag*)(Ax + ar * 128 + (kb ^ ((ar & 7) << 4)));
            int bc = colbase + (lane & 31);
            bfrag bf = *(const bfrag*)(Bx + bc * 128 + (kb ^ ((bc & 7) << 4)));
            acc = __builtin_amdgcn_mfma_f32_32x32x16_bf16(af, bf, acc, 0, 0, 0);
        }
    }
    __syncthreads();
#pragma unroll
    for (int reg = 0; reg < 16; ++reg) {
        int row = rowbase + (reg & 3) + 8 * (reg >> 2) + 4 * (lane >> 5);
        int col = colbase + (lane & 31);
        *(unsigned short*)(Ax + row * 128 + ((col * 2) ^ ((row & 7) << 4))) = f2bf(acc[reg]);
    }
    __syncthreads();
    {
        const int col_l = t & 63;
        unsigned short* dstbase = hB + (size_t)head * 524288 + (size_t)(n0 >> 6) * 8192
                                     + (size_t)(ob + col_l) * 8;
#pragma unroll
        for (int g = 0; g < 2; ++g) {
            int o8 = (t >> 6) + g * 4;
            int ks = o8 >> 1, lg = o8 & 1;
            alignas(16) unsigned short buf[8];
#pragma unroll
            for (int j = 0; j < 8; ++j) {
                int r = o8 * 8 + j;
                buf[j] = *(const unsigned short*)(Ax + r * 128 + ((col_l * 2) ^ ((r & 7) << 4)));
            }
            *(us8*)(dstbase + ks * 2048 + lg * 1024) = *(const us8*)buf;
        }
    }
}

// ---------------- kernel 2: ei[n,k], ejT[k,n] from hB (pre-scaled by log2e) ----------------
__global__ __launch_bounds__(256) void e2_kernel(const unsigned short* __restrict__ hB,
                                                 const float* __restrict__ a,
                                                 float* __restrict__ ei,
                                                 float* __restrict__ ejT) {
    __shared__ unsigned short hs[8192];
    __shared__ float as[128], ad[128];
    __shared__ float pim[4][64], pjm[4][64];
    const int t = threadIdx.x;
    const int k = blockIdx.x >> 6;
    const int mc = blockIdx.x & 63;
    if (t < 128) as[t] = a[k * 256 + t] * LOG2E;
    else         ad[t - 128] = a[k * 256 + t] * LOG2E;
    const unsigned short* src = hB + ((size_t)k * 64 + mc) * 8192;
#pragma unroll
    for (int i = 0; i < 4; ++i) {
        int off = i * 2048 + t * 8;
        *(us8*)&hs[off] = *(const us8*)&src[off];
    }
    __syncthreads();
    const int m = t & 63, wq = t >> 6;
    const int base = (m >> 4) * 2048 + ((m >> 3) & 1) * 1024 + (m & 7);
    float si = 0.f, sj = 0.f;
#pragma unroll
    for (int cc = 0; cc < 32; ++cc) {
        int c = wq * 32 + cc;
        float v = bf2f(hs[base + c * 8]);
        si += v * as[c];
        sj += v * ad[c];
    }
    pim[wq][m] = si; pjm[wq][m] = sj;
    __syncthreads();
    if (t < 64) {
        ei[(mc * 64 + t) * KHc + k]        = pim[0][t] + pim[1][t] + pim[2][t] + pim[3][t];
        ejT[(size_t)k * NN + mc * 64 + t]  = pjm[0][t] + pjm[1][t] + pjm[2][t] + pjm[3][t];
    }
}

// ---------------- kernel 3: out = softmax(P) @ H, full m, 8 waves ----------------
// 512 blocks x 512 threads; 8 waves x private 512-m slice, register-P, zero
// in-loop barriers. Flat 32-step loop, 1-step software-pipelined B-fragment
// prefetch. NO min-waves hint: grid (2 blocks/CU) caps occupancy anyway; the
// hint at 4 capped VGPRs at 64 and caused catastrophic spill (R14: 251 MB
// scratch writes). unroll 1 keeps live ranges small.
__global__ __launch_bounds__(512) void out_mfma_kernel(const unsigned* __restrict__ bits,
                                                       const float* __restrict__ ei,
                                                       const float* __restrict__ ejT,
                                                       const unsigned short* __restrict__ hB,
                                                       float* __restrict__ out) {
    __shared__ unsigned bitsL[8][544];      // 32 rows x 17 (16 words + pad) per wave
    __shared__ float ejPL[4096];            // [8][512]; reused as red after loop
    __shared__ float ejNL[4096];            // [8][512]
    __shared__ float sred[8][32];
    __shared__ float lsum[32];
    const int bid = blockIdx.x;
    const int nb  = (bid & 7) * 64 + (bid >> 3);    // bijective: 512 = 8*64
    const int k   = nb >> 7;
    const int n0  = (nb & 127) * 32;
    const int t = threadIdx.x, lane = t & 63, w = t >> 6;
    const int row = lane & 31, kh = lane >> 5;
    const int mq  = w * 512;                        // wave's private m range
    {   // stage bits (wave-private): lane pair covers one row (16 words)
        int r = lane >> 1, cb = (lane & 1) * 8;
        const unsigned* src = &bits[(size_t)(n0 + r) * 128 + (mq >> 5) + cb];
        unsigned* dst = &bitsL[w][r * 17 + cb];
#pragma unroll
        for (int c = 0; c < 8; ++c) dst[c] = src[c];
    }
    {   // stage EjP/EjN (wave-private): 8 columns per lane, exp2 once per column
        const float* src = &ejT[(size_t)k * NN + mq + lane * 8];
        f4 v0 = *(const f4*)src;
        f4 v1 = *(const f4*)(src + 4);
        float* dP = &ejPL[w * 512 + lane * 8];
        float* dN = &ejNL[w * 512 + lane * 8];
#pragma unroll
        for (int c = 0; c < 4; ++c) {
            dP[c]     = exp2f(v0[c]);
            dP[c + 4] = exp2f(v1[c]);
            dN[c]     = exp2f(0.2f * v0[c]);
            dN[c + 4] = exp2f(0.2f * v1[c]);
        }
    }
    const float eiv = ei[(n0 + row) * KHc + k];
    const float C = exp2f(-0.8f * eiv);
    const char* hp = (const char*)hB + (size_t)k * 1048576 + (size_t)(mq >> 6) * 16384
                     + kh * 2048 + row * 16;
    bfrag ones;
#pragma unroll
    for (int j = 0; j < 8; ++j) ones[j] = (short)0x3F80;   // bf16 1.0
    f16v acc0 = {}, acc1 = {}, acc2 = {}, acc3 = {}, accs = {};

    // software pipeline: prefetch step 0
    us8 c0v = *(const us8*)(hp);
    us8 c1v = *(const us8*)(hp + 512);
    us8 c2v = *(const us8*)(hp + 1024);
    us8 c3v = *(const us8*)(hp + 1536);

#pragma unroll 1
    for (int s = 0; s < 32; ++s) {
        const char* hn = hp + 4096;
        // prefetch step s+1 (at s=31 reads <=2KB past plane: still inside d_ws, discarded)
        us8 n0v = *(const us8*)(hn);
        us8 n1v = *(const us8*)(hn + 512);
        us8 n2v = *(const us8*)(hn + 1024);
        us8 n3v = *(const us8*)(hn + 1536);
        // P-gen for step s
        unsigned bw = bitsL[w][row * 17 + (s >> 1)] >> (((s & 1) << 4) + kh * 8);
        const int eb = w * 512 + s * 16 + kh * 8;
        f4 jp0 = *(const f4*)&ejPL[eb];
        f4 jp1 = *(const f4*)&ejPL[eb + 4];
        f4 jn0 = *(const f4*)&ejNL[eb];
        f4 jn1 = *(const f4*)&ejNL[eb + 4];
        float p[8];
#pragma unroll
        for (int j = 0; j < 8; ++j) {
            float jp = (j < 4) ? jp0[j] : jp1[j - 4];
            float jn = (j < 4) ? jn0[j] : jn1[j - 4];
            float v = fmaxf(jp, C * jn);           // exp2(lrelu(s))/exp2(ei)
            p[j] = ((bw >> j) & 1) ? v : 0.f;
        }
        union { unsigned u[4]; bfrag s2; } pk;
#pragma unroll
        for (int j = 0; j < 4; ++j) {
            float2 fp; fp.x = p[2 * j]; fp.y = p[2 * j + 1];
            __hip_bfloat162 b2 = __float22bfloat162_rn(fp);
            pk.u[j] = *reinterpret_cast<unsigned*>(&b2);
        }
        __builtin_amdgcn_s_setprio(1);
        acc0 = __builtin_amdgcn_mfma_f32_32x32x16_bf16(pk.s2, us2bf(c0v), acc0, 0, 0, 0);
        acc1 = __builtin_amdgcn_mfma_f32_32x32x16_bf16(pk.s2, us2bf(c1v), acc1, 0, 0, 0);
        acc2 = __builtin_amdgcn_mfma_f32_32x32x16_bf16(pk.s2, us2bf(c2v), acc2, 0, 0, 0);
        acc3 = __builtin_amdgcn_mfma_f32_32x32x16_bf16(pk.s2, us2bf(c3v), acc3, 0, 0, 0);
        accs = __builtin_amdgcn_mfma_f32_32x32x16_bf16(pk.s2, ones, accs, 0, 0, 0);
        __builtin_amdgcn_s_setprio(0);
        c0v = n0v; c1v = n1v; c2v = n2v; c3v = n3v;
        hp = hn;
    }
    // publish per-wave row sums
    if (row == 0) {   // lanes 0 and 32 of each wave
#pragma unroll
        for (int reg = 0; reg < 16; ++reg) {
            int r = (reg & 3) + 8 * (reg >> 2) + 4 * kh;
            sred[w][r] = accs[reg];
        }
    }
    __syncthreads();
    if (t < 32) {
        float s = ((sred[0][t] + sred[1][t]) + (sred[2][t] + sred[3][t]))
                + ((sred[4][t] + sred[5][t]) + (sred[6][t] + sred[7][t]));
        lsum[t] = 1.0f / s;
    }
    // sequential reduce of acc partials into w0 (red overlays dead ejPL plane)
    float* red = ejPL;
#pragma unroll
    for (int src = 1; src < 8; ++src) {
        if (w == src) {
#pragma unroll
            for (int cg = 0; cg < 4; ++cg) {
                const f16v& av = (cg == 0) ? acc0 : (cg == 1) ? acc1 : (cg == 2) ? acc2 : acc3;
#pragma unroll
                for (int reg = 0; reg < 16; ++reg) {
                    int r = (reg & 3) + 8 * (reg >> 2) + 4 * kh;
                    red[r * 128 + cg * 32 + row] = av[reg];
                }
            }
        }
        __syncthreads();
        if (w == 0) {
#pragma unroll
            for (int cg = 0; cg < 4; ++cg) {
                f16v& av = (cg == 0) ? acc0 : (cg == 1) ? acc1 : (cg == 2) ? acc2 : acc3;
#pragma unroll
                for (int reg = 0; reg < 16; ++reg) {
                    int r = (reg & 3) + 8 * (reg >> 2) + 4 * kh;
                    av[reg] += red[r * 128 + cg * 32 + row];
                }
            }
        }
        __syncthreads();
    }
    if (w == 0) {
#pragma unroll
        for (int cg = 0; cg < 4; ++cg) {
            const f16v& av = (cg == 0) ? acc0 : (cg == 1) ? acc1 : (cg == 2) ? acc2 : acc3;
#pragma unroll
            for (int reg = 0; reg < 16; ++reg) {
                int r = (reg & 3) + 8 * (reg >> 2) + 4 * kh;
                out[(size_t)(n0 + r) * KFc + k * FOUTc + cg * 32 + row] = av[reg] * lsum[r];
            }
        }
    }
}

extern "C" void kernel_launch(void* const* d_in, const int* in_sizes, int n_in,
                              void* d_out, int out_size, void* d_ws, size_t ws_size,
                              hipStream_t stream) {
    const float* x   = (const float*)d_in[0];
    const int*   adj = (const int*)d_in[1];
    const float* W   = (const float*)d_in[2];
    const float* a   = (const float*)d_in[3];
    float* out = (float*)d_out;
    char* ws = (char*)d_ws;

    unsigned short* hB   = (unsigned short*)ws;                  // 0..4 MB
    unsigned short* xb   = (unsigned short*)(ws + (4u << 20));   // 4..8 MB
    unsigned short* WbT  = (unsigned short*)(ws + (20u << 20));  // 20..20.5 MB
    unsigned*       bits = (unsigned*)(ws + (21u << 20));        // 21..23 MB
    float*          ei   = (float*)(ws + (23u << 20));           // 64 KB
    float*          ejT  = ei + (size_t)NN * KHc;                // 64 KB

    prep_kernel<<<1088, 256, 0, stream>>>(x, W, xb, WbT);
    gemmh_bits_kernel<<<1536, 256, 0, stream>>>(xb, WbT, adj, hB, bits);
    e2_kernel<<<256, 256, 0, stream>>>(hB, a, ei, ejT);
    out_mfma_kernel<<<512, 512, 0, stream>>>(bits, ei, ejT, hB, out);
}